// Round 6
// baseline (243.464 us; speedup 1.0000x reference)
//
#include <hip/hip_runtime.h>
#include <math.h>

// EqualtimeLayer R19: barrier-free wave-private solver.
// R13..R18 post-mortem: every block-cooperative variant (78-115us) is bound by
// the per-batch __syncthreads chain (5-9 barriers x 8 batches, all 4 waves
// convoying at each), with achieved residency ~= 0.7 x blocks/CU cap. Issue
// and bank-conflict reductions moved nothing; LDS footprint and barrier count
// moved everything.
// R19: each wave owns 2 of the WG's 8 batches end-to-end. Per-wave 256-bucket
// region + 256-slot (t,w) buffer; hist/scan/scatter/solve all wave-internal
// (no __syncthreads in the batch loop; one barrier total, after the column
// stage). Carries via readlane. Scatter rank = atomic bump of the packed
// offset field (+1<<12 returns position; no rnk/bkt arrays). Next-event check
// via exact lazy bucket lookup (bucket time ranges are disjoint+ordered):
// tmp <= edge(k+1) validates candidates arithmetically; only gap-spanning
// candidates (tmp in (edge, tHi]) read the next bucket's members.
// Unified window loop: window [tLo,tHi), events beyond tracked by minBeyond;
// next window starts at tLo=minBeyond (strictly separates processed from
// unprocessed -- no float-boundary double/missed counting). Handles the tail
// fallback AND the N>CAP overflow (B1 bucket cut) exactly, zero fast-path cost.
// LDS 20KB -> 8 blocks/CU possible. Est. ~50 VGPR peak (launch_bounds(256,8);
// WRITE_SIZE is the spill tripwire).

#define B_TOT 32
#define PRE 1024
#define POST 1024
#define TPB 256
#define BPW 8          // batches per WG
#define BPWAVE 2       // batches per wave
#define NBW 256        // buckets per wave
#define CAP 256        // event-buffer slots per wave
#define TCUTF 0.625f

// ---- DPP helpers (gfx9 encodings; proven in R13+) ----
template<int CTRL, int MASK>
__device__ __forceinline__ int dpp_add_i32(int v) {
    return v + __builtin_amdgcn_update_dpp(0, v, CTRL, MASK, 0xf, true);
}
template<int CTRL, int MASK>
__device__ __forceinline__ float dpp_add_f32(float v) {
    int t = __builtin_amdgcn_update_dpp(0, __float_as_int(v), CTRL, MASK, 0xf, true);
    return v + __int_as_float(t);
}
template<int CTRL>
__device__ __forceinline__ float dpp_min_f32(float v) {
    int t = __builtin_amdgcn_update_dpp(__float_as_int(v), __float_as_int(v), CTRL, 0xf, 0xf, false);
    return fminf(v, __int_as_float(t));
}
__device__ __forceinline__ int wave_iscan_i32(int v) {
    v = dpp_add_i32<0x111, 0xf>(v);
    v = dpp_add_i32<0x112, 0xf>(v);
    v = dpp_add_i32<0x114, 0xf>(v);
    v = dpp_add_i32<0x118, 0xf>(v);
    v = dpp_add_i32<0x142, 0xa>(v);
    v = dpp_add_i32<0x143, 0xc>(v);
    return v;
}
__device__ __forceinline__ float wave_iscan_f32(float v) {
    v = dpp_add_f32<0x111, 0xf>(v);
    v = dpp_add_f32<0x112, 0xf>(v);
    v = dpp_add_f32<0x114, 0xf>(v);
    v = dpp_add_f32<0x118, 0xf>(v);
    v = dpp_add_f32<0x142, 0xa>(v);
    v = dpp_add_f32<0x143, 0xc>(v);
    return v;
}
__device__ __forceinline__ float wave_min_f32(float v) {
    v = fminf(v, __shfl_down(v, 32));
    v = fminf(v, __shfl_down(v, 16));
    v = dpp_min_f32<0x140>(v);
    v = dpp_min_f32<0x141>(v);
    v = dpp_min_f32<0x4E>(v);
    v = dpp_min_f32<0xB1>(v);
    return v;
}
// min over wave, broadcast to all lanes (lane 0 holds result; all lanes active)
__device__ __forceinline__ float wave_min_bcast(float v) {
    v = wave_min_f32(v);
    return __int_as_float(__builtin_amdgcn_readfirstlane(__float_as_int(v)));
}
// butterfly max, result in all lanes (rare path)
__device__ __forceinline__ int wave_red_max_i32(int v) {
    v = max(v, __shfl_xor(v, 32));
    v = max(v, __shfl_xor(v, 16));
    v = max(v, __shfl_xor(v, 8));
    v = max(v, __shfl_xor(v, 4));
    v = max(v, __shfl_xor(v, 2));
    v = max(v, __shfl_xor(v, 1));
    return v;
}
__device__ __forceinline__ float bcast_f32(float v, int l) {
    return __int_as_float(__builtin_amdgcn_readlane(__float_as_int(v), l));
}

__global__ __launch_bounds__(TPB, 8) void equaltime_kernel(
    const float* __restrict__ spikes,     // [B][PRE]
    const float* __restrict__ weights,    // [PRE][POST]
    const float* __restrict__ delays,     // [PRE][POST]
    const float* __restrict__ thresholds, // [POST]
    float* __restrict__ out)              // [B][POST]
{
    __shared__ __align__(16) float s_d[PRE];       // 4 KB column delays
    __shared__ __align__(16) float s_ww[PRE];      // 4 KB column weights
    __shared__ __align__(16) float s_t[4][CAP];    // 4 KB scattered times
    __shared__ __align__(16) float s_w[4][CAP];    // 4 KB scattered weights
    __shared__ __align__(16) int   s_pk[4][NBW];   // 4 KB counts -> off<<12|cnt

    const int tid  = threadIdx.x;
    const int lane = tid & 63;
    const int wid  = tid >> 6;

    // XCD-contiguous swizzle for weight/delay L2 locality
    const int bx   = blockIdx.x;
    const int sbx  = (bx & 7) * 512 + (bx >> 3);
    const int post = sbx >> 2;            // 4 WGs per post
    const int b0   = (sbx & 3) * BPW;
    const float theta = thresholds[post];

    // ---- cooperative column stage (the ONLY barrier) ----
#pragma unroll
    for (int i = 0; i < 4; ++i) {
        int pre = tid + i * TPB;
        s_d[pre]  = delays[pre * POST + post];
        s_ww[pre] = weights[pre * POST + post];
    }
    reinterpret_cast<int4*>(s_pk[wid])[lane] = make_int4(0, 0, 0, 0);
    __syncthreads();

    float* st = s_t[wid];
    float* sw = s_w[wid];
    int*   pk = s_pk[wid];

    for (int bi = 0; bi < BPWAVE; ++bi) {
        const int b = b0 + wid * BPWAVE + bi;
        const float4* spb = reinterpret_cast<const float4*>(spikes + b * PRE);

        float tLo = 0.f, tHi = TCUTF;     // current window
        float Wb = 0.f, WTb = 0.f;        // sums over prior windows
        float mAll = INFINITY;

        for (int iter = 0; iter < 16; ++iter) {
            const float wdt  = tHi - tLo;
            const float scl  = 256.f / wdt;
            const float invb = wdt * (1.f / 256.f);

            // lane handles pres {lane*4 + g*256 + i}: coalesced float4 loads
            float4 sp0 = spb[lane], sp1 = spb[lane + 64],
                   sp2 = spb[lane + 128], sp3 = spb[lane + 192];

            // ---- hist (counts only; wave-private region) ----
#pragma unroll
            for (int g = 0; g < 4; ++g) {
                float4 sp = (g == 0) ? sp0 : (g == 1) ? sp1 : (g == 2) ? sp2 : sp3;
                float4 d4 = reinterpret_cast<const float4*>(s_d)[lane + 64 * g];
                float tv[4] = {sp.x + d4.x, sp.y + d4.y, sp.z + d4.z, sp.w + d4.w};
#pragma unroll
                for (int i = 0; i < 4; ++i) {
                    if (tv[i] >= tLo && tv[i] < tHi) {
                        int k = (int)((tv[i] - tLo) * scl);
                        k = k > 255 ? 255 : k;
                        atomicAdd(&pk[k], 1);
                    }
                }
            }

            // ---- wave-local scan, in place -> off<<12|cnt ----
            int4 a = *reinterpret_cast<int4*>(&pk[lane * 4]);
            int c[4] = {a.x, a.y, a.z, a.w};
            int ls[4]; int s = 0;
#pragma unroll
            for (int j = 0; j < 4; ++j) { s += c[j]; ls[j] = s; }
            int x = wave_iscan_i32(s);
            int e = x - s;
            int tot = __builtin_amdgcn_readlane(x, 63);
            int incl[4];
#pragma unroll
            for (int j = 0; j < 4; ++j) incl[j] = e + ls[j];
            int B1 = NBW, Nw = tot;
            if (tot > CAP) {               // rare: cut window at bucket B1
                int cle = 0, mx = 0;
#pragma unroll
                for (int j = 0; j < 4; ++j)
                    if (incl[j] <= CAP) { ++cle; mx = incl[j] > mx ? incl[j] : mx; }
                int bs = wave_iscan_i32(cle);
                B1 = __builtin_amdgcn_readlane(bs, 63);
                Nw = wave_red_max_i32(mx); // = off[B1]
            }
            int o[4];
#pragma unroll
            for (int j = 0; j < 4; ++j) o[j] = ((incl[j] - c[j]) << 12) | c[j];
            *reinterpret_cast<int4*>(&pk[lane * 4]) = make_int4(o[0], o[1], o[2], o[3]);

            // ---- scatter (atomic bump of offset field returns position) ----
            float mB = INFINITY;           // min t over unprocessed events
#pragma unroll
            for (int g = 0; g < 4; ++g) {
                float4 sp = (g == 0) ? sp0 : (g == 1) ? sp1 : (g == 2) ? sp2 : sp3;
                float4 d4 = reinterpret_cast<const float4*>(s_d)[lane + 64 * g];
                float4 w4 = reinterpret_cast<const float4*>(s_ww)[lane + 64 * g];
                float tv[4] = {sp.x + d4.x, sp.y + d4.y, sp.z + d4.z, sp.w + d4.w};
                float wv[4] = {w4.x, w4.y, w4.z, w4.w};
#pragma unroll
                for (int i = 0; i < 4; ++i) {
                    float tvv = tv[i];
                    if (tvv < tLo) continue;           // processed earlier
                    bool put = false;
                    if (tvv < tHi) {
                        int k = (int)((tvv - tLo) * scl);
                        k = k > 255 ? 255 : k;
                        if (k < B1) {
                            int old = atomicAdd(&pk[k], 4096);
                            int pos = old >> 12;       // off + arrivals
                            st[pos] = tvv;
                            sw[pos] = wv[i];
                            put = true;
                        }
                    }
                    if (!put) mB = fminf(mB, tvv);
                }
            }
            mB = wave_min_bcast(mB);

            // ---- solve (wave-sequential sub-chunks, carries in registers) ----
            float carW = 0.f, carWT = 0.f, mc = INFINITY;
            for (int c0 = 0; c0 < Nw; c0 += 64) {
                int p = c0 + lane;
                bool in = p < Nw;
                float tp = in ? st[p] : 0.f;
                float wp = in ? sw[p] : 0.f;
                float xw  = wave_iscan_f32(wp);
                float xwt = wave_iscan_f32(wp * tp);
                float W  = Wb + carW + xw;             // inclusive @ p, pos order
                float WT = WTb + carWT + xwt;
                carW  += bcast_f32(xw, 63);
                carWT += bcast_f32(xwt, 63);
                if (in) {
                    int k = (int)((tp - tLo) * scl);
                    k = k > 255 ? 255 : k;
                    int v  = pk[k];
                    int cn = v & 0xfff;
                    int q0 = v >> 12;                  // bucket end (off+cnt)
                    int bas = q0 - cn;
                    float tnx = INFINITY;              // later mates min
                    if (cn > 1) {
                        for (int q = bas; q < q0; ++q) {
                            if (q == p) continue;
                            float tq = st[q], wq = sw[q];
                            bool earlier = (tq < tp) || (tq == tp && q < p);
                            bool posb = q < p;
                            W  += (earlier ? wq      : 0.f) - (posb ? wq      : 0.f);
                            WT += (earlier ? wq * tq : 0.f) - (posb ? wq * tq : 0.f);
                            if (!earlier) tnx = fminf(tnx, tq);
                        }
                    }
                    if (W > 0.f) {
                        float tmp = (theta + WT) * __builtin_amdgcn_rcpf(W);
                        if (tmp >= tp && tmp <= tnx) {
                            // bucket ranges are disjoint+ordered: tmp <= edge
                            // proves tmp <= every later-bucket event
                            float edge = tLo + (float)(k + 1) * invb;
                            bool val = true;
                            if (tmp > edge) {
                                float nxt;
                                if (q0 >= Nw) nxt = mB;          // last bucket
                                else if (tmp > tHi) nxt = -1.f;  // later in-window event < tHi < tmp
                                else {                           // exact: next bucket min
                                    float t1 = st[q0];
                                    int k2 = (int)((t1 - tLo) * scl);
                                    k2 = k2 > 255 ? 255 : k2;
                                    int v2 = pk[k2];
                                    int cn2 = v2 & 0xfff;
                                    int b2 = (v2 >> 12) - cn2;
                                    nxt = t1;
                                    for (int q = b2; q < b2 + cn2; ++q)
                                        nxt = fminf(nxt, st[q]);
                                }
                                val = tmp <= nxt;
                            }
                            if (val) mc = fminf(mc, tmp);
                        }
                    }
                }
            }
            mc = wave_min_bcast(mc);
            // re-zero own bucket region (after all pk reads; wave order)
            reinterpret_cast<int4*>(pk)[lane] = make_int4(0, 0, 0, 0);

            if (mc < INFINITY) { mAll = mc; break; }   // later windows' tmp >= mB >= mc
            if (!(mB < INFINITY)) break;               // no events remain -> INF
            Wb += carW; WTb += carWT;
            tLo = mB;                                  // strict cut: processed < mB <= unprocessed
            tHi = 2.0f;                                // tv = spike+delay < 2 always
        }

        if (lane == 0) out[b * POST + post] = mAll;
    }
}

extern "C" void kernel_launch(void* const* d_in, const int* in_sizes, int n_in,
                              void* d_out, int out_size, void* d_ws, size_t ws_size,
                              hipStream_t stream) {
    const float* spikes     = (const float*)d_in[0]; // [32,1024]
    const float* weights    = (const float*)d_in[1]; // [1024,1024]
    const float* delays     = (const float*)d_in[2]; // [1024,1024]
    const float* thresholds = (const float*)d_in[3]; // [1024]
    float* outp = (float*)d_out;                     // [32,1024]

    dim3 grid(POST * (B_TOT / BPW)); // 4096 workgroups
    dim3 block(TPB);
    equaltime_kernel<<<grid, block, 0, stream>>>(spikes, weights, delays, thresholds, outp);
}